// Round 7
// baseline (458.768 us; speedup 1.0000x reference)
//
#include <hip/hip_runtime.h>
#include <hip/hip_bf16.h>
#include <math.h>

#define B_ 32
#define S_ 197
#define D_ 768
#define H_ 12
#define P_ 196
#define KN_ 32
#define HD_ 64
#define DFF_ 3072
#define M_ (B_ * S_)   // 6304

typedef __attribute__((ext_vector_type(8))) short short8;
typedef __attribute__((ext_vector_type(8))) __bf16 bf16x8;
typedef __attribute__((ext_vector_type(4))) float f32x4;
typedef __attribute__((ext_vector_type(4))) float float4v;

static __device__ __forceinline__ unsigned short f2bf(float f) {
    unsigned u = __builtin_bit_cast(unsigned, f);
    u += 0x7FFFu + ((u >> 16) & 1u);
    return (unsigned short)(u >> 16);
}
static __device__ __forceinline__ float bf2f(unsigned short s) {
    unsigned u = ((unsigned)s) << 16;
    return __builtin_bit_cast(float, u);
}

// async global -> LDS, 16 B per lane; LDS base wave-uniform (HW adds lane*16).
static __device__ __forceinline__ void gload_lds16(const void* g, void* l) {
    __builtin_amdgcn_global_load_lds(
        (const __attribute__((address_space(1))) unsigned int*)g,
        (__attribute__((address_space(3))) unsigned int*)l, 16, 0, 0);
}

// ---------- fused fp32->bf16 convert + transpose: in[K][N] -> out[N][K] ----------
__global__ void __launch_bounds__(256) cvt_t_kernel(const float* __restrict__ in,
        unsigned short* __restrict__ out, int K, int N) {
    __shared__ float tile[32][33];
    int nt = N >> 5;
    int bx = blockIdx.x % nt;
    int by = blockIdx.x / nt;
    int n0 = bx << 5, k0 = by << 5;
    int tx = threadIdx.x & 31, ty = threadIdx.x >> 5;
    #pragma unroll
    for (int i = 0; i < 32; i += 8)
        tile[ty + i][tx] = in[(size_t)(k0 + ty + i) * N + n0 + tx];
    __syncthreads();
    #pragma unroll
    for (int i = 0; i < 32; i += 8)
        out[(size_t)(n0 + ty + i) * K + k0 + tx] = f2bf(tile[tx][ty + i]);
}

// ---------------- LayerNorm (fp32 in, bf16 out) ----------------
__global__ void __launch_bounds__(256) ln_kernel(const float* __restrict__ x,
        const float* __restrict__ g, const float* __restrict__ bt,
        unsigned short* __restrict__ out) {
    int row = blockIdx.x;
    int tid = threadIdx.x;
    const float* xr = x + (size_t)row * D_;
    float v0 = xr[tid], v1 = xr[tid + 256], v2 = xr[tid + 512];
    float s = v0 + v1 + v2;
    float q = v0 * v0 + v1 * v1 + v2 * v2;
    #pragma unroll
    for (int o = 32; o >= 1; o >>= 1) {
        s += __shfl_xor(s, o);
        q += __shfl_xor(q, o);
    }
    __shared__ float red[8];
    int wave = tid >> 6, lane = tid & 63;
    if (lane == 0) { red[wave] = s; red[4 + wave] = q; }
    __syncthreads();
    float S0 = red[0] + red[1] + red[2] + red[3];
    float Q0 = red[4] + red[5] + red[6] + red[7];
    float mean = S0 * (1.0f / D_);
    float var = Q0 * (1.0f / D_) - mean * mean;
    float rstd = rsqrtf(var + 1e-5f);
    unsigned short* orow = out + (size_t)row * D_;
    orow[tid]       = f2bf((v0 - mean) * rstd * g[tid]       + bt[tid]);
    orow[tid + 256] = f2bf((v1 - mean) * rstd * g[tid + 256] + bt[tid + 256]);
    orow[tid + 512] = f2bf((v2 - mean) * rstd * g[tid + 512] + bt[tid + 512]);
}

// ------- bf16 MFMA GEMM: C = A[M,K] @ Bt[N,K]^T + bias -------
// global_load_lds staging, LDS double-buffer with COUNTED vmcnt (prefetch
// stays in flight across barriers), both-sides XOR swizzle.
// EPI 0: store bf16.  EPI 1: gelu(exact) then store bf16.  EPI 2: +resid, fp32.
template<int BM, int BN, int EPI>
__global__ void __launch_bounds__(256) gemm_kernel(
        const unsigned short* __restrict__ A,
        const unsigned short* __restrict__ Bt,
        const float* __restrict__ bias,
        const float* __restrict__ resid,
        void* __restrict__ outp,
        int M, int N, int K) {
    constexpr int BK = 64;
    constexpr int WM = BM / 2, WN = BN / 2;
    constexpr int MR = WM / 16, NR = WN / 16;
    constexpr int ACH = BM / 8;   // 1KB chunks (8 rows x 128B)
    constexpr int BCH = BN / 8;
    static_assert(ACH / 4 + BCH / 4 == 8, "vmcnt literal assumes 8 loads/wave/tile");
    constexpr int ASZ = BM * BK, BSZ = BN * BK;
    __shared__ short As[2 * ASZ];
    __shared__ short Bs[2 * BSZ];

    // bijective XCD-chunked swizzle (m204)
    int nwg = gridDim.x;
    int orig = blockIdx.x;
    int q8 = nwg >> 3, r8 = nwg & 7;
    int xcd = orig & 7, idx = orig >> 3;
    int wg = (xcd < r8 ? xcd * (q8 + 1) : r8 * (q8 + 1) + (xcd - r8) * q8) + idx;

    int ntn = N / BN;
    int bm = (wg / ntn) * BM;
    int bn = (wg % ntn) * BN;
    int tid = threadIdx.x;
    int lane = tid & 63;
    int wave = tid >> 6;
    int wm = (wave >> 1) * WM, wn = (wave & 1) * WN;
    int lr = lane & 15;
    int lk0 = (lane >> 4) << 3;               // 0,8,16,24 (shorts)
    int crow = lane >> 3;                     // row within 8-row chunk
    // pre-swizzled source col (shorts): involution of the read-side XOR
    int scol = (((lane & 7) ^ ((lane >> 3) & 7)) << 3);
    int rsw = (lr & 7) << 3;                  // read-side XOR (shorts)

    f32x4 acc[MR][NR] = {};

    auto stage = [&](int kt, int buf) {
        short* Ad = &As[buf * ASZ];
        short* Bd = &Bs[buf * BSZ];
        #pragma unroll
        for (int c = wave; c < ACH; c += 4) {
            int grow = bm + c * 8 + crow;
            if (grow >= M) grow = M - 1;   // row m of A only affects row m of C
            gload_lds16(A + (size_t)grow * K + kt + scol, &Ad[c * 512]);
        }
        #pragma unroll
        for (int c = wave; c < BCH; c += 4) {
            int grow = bn + c * 8 + crow;
            gload_lds16(Bt + (size_t)grow * K + kt + scol, &Bd[c * 512]);
        }
    };

    int nt = K / BK;
    stage(0, 0);   // 8 loads in flight

    for (int t = 0; t < nt; ++t) {
        int cur = t & 1;
        if (t + 1 < nt) {
            stage((t + 1) * BK, cur ^ 1);   // 8 more loads into other buffer
            // wait for tile t's 8 loads; tile t+1's 8 stay in flight
            asm volatile("s_waitcnt vmcnt(8)" ::: "memory");
        } else {
            asm volatile("s_waitcnt vmcnt(0)" ::: "memory");
        }
        __builtin_amdgcn_s_barrier();          // all waves: tile t resident
        __builtin_amdgcn_sched_barrier(0);     // pin ds_reads below barrier
        const short* Ab = &As[cur * ASZ];
        const short* Bb = &Bs[cur * BSZ];
        __builtin_amdgcn_s_setprio(1);
        #pragma unroll
        for (int kk = 0; kk < 2; ++kk) {
            int lkb = lk0 + kk * 32;
            bf16x8 af[MR], bfv[NR];
            #pragma unroll
            for (int m = 0; m < MR; ++m)
                af[m] = __builtin_bit_cast(bf16x8,
                    *(const short8*)(&Ab[(wm + m * 16 + lr) * BK + (lkb ^ rsw)]));
            #pragma unroll
            for (int n = 0; n < NR; ++n)
                bfv[n] = __builtin_bit_cast(bf16x8,
                    *(const short8*)(&Bb[(wn + n * 16 + lr) * BK + (lkb ^ rsw)]));
            #pragma unroll
            for (int m = 0; m < MR; ++m)
                #pragma unroll
                for (int n = 0; n < NR; ++n)
                    acc[m][n] = __builtin_amdgcn_mfma_f32_16x16x32_bf16(
                        af[m], bfv[n], acc[m][n], 0, 0, 0);
        }
        __builtin_amdgcn_s_setprio(0);
        __builtin_amdgcn_sched_barrier(0);     // keep reads above next barrier
        if (t + 1 < nt)
            __builtin_amdgcn_s_barrier();      // reads done -> next stage may overwrite
    }

    int r0 = (lane >> 4) << 2;
    #pragma unroll
    for (int m = 0; m < MR; ++m) {
        #pragma unroll
        for (int n = 0; n < NR; ++n) {
            int col = bn + wn + n * 16 + lr;
            #pragma unroll
            for (int r = 0; r < 4; ++r) {
                int row = bm + wm + m * 16 + r0 + r;
                if (row < M) {
                    float v = acc[m][n][r] + bias[col];
                    if (EPI == 1)
                        v = 0.5f * v * (1.0f + erff(v * 0.70710678118f));
                    if (EPI == 2) {
                        ((float*)outp)[(size_t)row * N + col] =
                            v + resid[(size_t)row * N + col];
                    } else {
                        ((unsigned short*)outp)[(size_t)row * N + col] = f2bf(v);
                    }
                }
            }
        }
    }
}

// ---------------- sparse patch attention: one wave per (b,h,p) ----------------
__global__ void __launch_bounds__(256) attn_patch_kernel(
        const unsigned short* __restrict__ qkv,
        const int* __restrict__ routes,
        unsigned short* __restrict__ out) {
    int wid = (blockIdx.x * 256 + threadIdx.x) >> 6;
    int lane = threadIdx.x & 63;
    int b = wid / (H_ * P_);
    int rem = wid - b * (H_ * P_);
    int h = rem / P_;
    int p = rem - h * P_;
    int ks = lane & 31, half = lane >> 5;
    int skey = routes[p * KN_ + ks] + 1;
    const unsigned short* Qrow = qkv + (size_t)(b * S_ + p + 1) * (3 * D_) + h * HD_;
    const unsigned short* Krow = qkv + (size_t)(b * S_ + skey) * (3 * D_) + D_ + h * HD_;
    float dot = 0.f;
    #pragma unroll
    for (int q = 0; q < 4; ++q) {
        short8 qv = *(const short8*)(Qrow + half * 32 + q * 8);
        short8 kv = *(const short8*)(Krow + half * 32 + q * 8);
        #pragma unroll
        for (int j = 0; j < 8; ++j)
            dot += bf2f((unsigned short)qv[j]) * bf2f((unsigned short)kv[j]);
    }
    dot += __shfl_xor(dot, 32);
    float sc = dot * 0.125f;
    float mx = sc;
    #pragma unroll
    for (int o = 16; o >= 1; o >>= 1) mx = fmaxf(mx, __shfl_xor(mx, o));
    float e = __expf(sc - mx);
    float ssum = e;
    #pragma unroll
    for (int o = 16; o >= 1; o >>= 1) ssum += __shfl_xor(ssum, o);
    float w = e / ssum;
    const unsigned short* Vb = qkv + (size_t)b * S_ * (3 * D_) + 2 * D_ + h * HD_;
    float o_acc = 0.f;
    #pragma unroll 4
    for (int k = 0; k < 32; ++k) {
        float wk = __shfl(w, k);
        int sk = __shfl(skey, k);
        o_acc += wk * bf2f(Vb[(size_t)sk * (3 * D_) + lane]);
    }
    out[(size_t)(b * S_ + p + 1) * D_ + h * HD_ + lane] = f2bf(o_acc);
}

// ---------------- dense CLS attention: one wave per (b,h) ----------------
__global__ void __launch_bounds__(256) attn_cls_kernel(
        const unsigned short* __restrict__ qkv,
        unsigned short* __restrict__ out) {
    int wid = (blockIdx.x * 256 + threadIdx.x) >> 6;
    int lane = threadIdx.x & 63;
    int b = wid / H_, h = wid - b * H_;
    int ks = lane & 31, half = lane >> 5;
    const unsigned short* base = qkv + (size_t)b * S_ * (3 * D_);
    const unsigned short* Qrow = base + h * HD_;
    short8 qv[4];
    #pragma unroll
    for (int q = 0; q < 4; ++q)
        qv[q] = *(const short8*)(Qrow + half * 32 + q * 8);
    float sc[7];
    #pragma unroll
    for (int c = 0; c < 7; ++c) {
        int key = c * 32 + ks;
        float dot = 0.f;
        if (key < S_) {
            const unsigned short* Krow =
                base + (size_t)key * (3 * D_) + D_ + h * HD_ + half * 32;
            #pragma unroll
            for (int q = 0; q < 4; ++q) {
                short8 kv = *(const short8*)(Krow + q * 8);
                #pragma unroll
                for (int j = 0; j < 8; ++j)
                    dot += bf2f((unsigned short)qv[q][j]) * bf2f((unsigned short)kv[j]);
            }
        }
        dot += __shfl_xor(dot, 32);
        sc[c] = (key < S_) ? dot * 0.125f : -1e30f;
    }
    float mx = -1e30f;
    #pragma unroll
    for (int c = 0; c < 7; ++c) mx = fmaxf(mx, sc[c]);
    #pragma unroll
    for (int o = 16; o >= 1; o >>= 1) mx = fmaxf(mx, __shfl_xor(mx, o));
    float e[7];
    float ssum = 0.f;
    #pragma unroll
    for (int c = 0; c < 7; ++c) { e[c] = __expf(sc[c] - mx); ssum += e[c]; }
    #pragma unroll
    for (int o = 16; o >= 1; o >>= 1) ssum += __shfl_xor(ssum, o);
    float inv = 1.f / ssum;
    const unsigned short* Vb = base + 2 * D_ + h * HD_;
    float o_acc = 0.f;
    for (int c = 0; c < 7; ++c) {
        for (int k = 0; k < 32; ++k) {
            int key = c * 32 + k;
            if (key < S_) {
                float wk = __shfl(e[c], k) * inv;
                o_acc += wk * bf2f(Vb[(size_t)key * (3 * D_) + lane]);
            }
        }
    }
    out[(size_t)(b * S_) * D_ + h * HD_ + lane] = f2bf(o_acc);
}

extern "C" void kernel_launch(void* const* d_in, const int* in_sizes, int n_in,
                              void* d_out, int out_size, void* d_ws, size_t ws_size,
                              hipStream_t stream) {
    const float* x      = (const float*)d_in[0];
    const int*   routes = (const int*)d_in[1];
    const float* qkv_w  = (const float*)d_in[2];
    const float* qkv_b  = (const float*)d_in[3];
    const float* proj_w = (const float*)d_in[4];
    const float* proj_b = (const float*)d_in[5];
    const float* n1_g   = (const float*)d_in[6];
    const float* n1_b   = (const float*)d_in[7];
    const float* n2_g   = (const float*)d_in[8];
    const float* n2_b   = (const float*)d_in[9];
    const float* w1     = (const float*)d_in[10];
    const float* b1     = (const float*)d_in[11];
    const float* w2     = (const float*)d_in[12];
    const float* b2     = (const float*)d_in[13];
    float* out = (float*)d_out;

    char* ws = (char*)d_ws;
    size_t off = 0;
    auto alloc = [&](size_t bytes) -> void* {
        void* p = ws + off;
        off += (bytes + 255) & ~(size_t)255;
        return p;
    };
    unsigned short* wq_bf  = (unsigned short*)alloc((size_t)D_ * 3 * D_ * 2);
    unsigned short* wp_bf  = (unsigned short*)alloc((size_t)D_ * D_ * 2);
    unsigned short* w1_bf  = (unsigned short*)alloc((size_t)D_ * DFF_ * 2);
    unsigned short* w2_bf  = (unsigned short*)alloc((size_t)DFF_ * D_ * 2);
    unsigned short* xn_bf  = (unsigned short*)alloc((size_t)M_ * D_ * 2);
    float*          x1     = (float*)alloc((size_t)M_ * D_ * 4);
    unsigned short* qkv_bf = (unsigned short*)alloc((size_t)M_ * 3 * D_ * 2);
    unsigned short* attn_bf= (unsigned short*)alloc((size_t)M_ * D_ * 2);
    unsigned short* h_bf   = qkv_bf;   // reuse (dead after attention)

    auto cvt_t = [&](const float* src, unsigned short* dst, int K, int N) {
        cvt_t_kernel<<<(N >> 5) * (K >> 5), 256, 0, stream>>>(src, dst, K, N);
    };
    cvt_t(qkv_w, wq_bf, D_, 3 * D_);
    cvt_t(proj_w, wp_bf, D_, D_);
    cvt_t(w1, w1_bf, D_, DFF_);
    cvt_t(w2, w2_bf, DFF_, D_);

    ln_kernel<<<M_, 256, 0, stream>>>(x, n1_g, n1_b, xn_bf);

    gemm_kernel<128, 128, 0><<<50 * (3 * D_ / 128), 256, 0, stream>>>(
        xn_bf, wq_bf, qkv_b, nullptr, qkv_bf, M_, 3 * D_, D_);

    attn_patch_kernel<<<(B_ * H_ * P_) / 4, 256, 0, stream>>>(qkv_bf, routes, attn_bf);
    attn_cls_kernel<<<(B_ * H_) / 4, 256, 0, stream>>>(qkv_bf, attn_bf);

    gemm_kernel<128, 128, 2><<<50 * (D_ / 128), 256, 0, stream>>>(
        attn_bf, wp_bf, proj_b, x, x1, M_, D_, D_);

    ln_kernel<<<M_, 256, 0, stream>>>(x1, n2_g, n2_b, xn_bf);

    gemm_kernel<128, 128, 1><<<50 * (DFF_ / 128), 256, 0, stream>>>(
        xn_bf, w1_bf, b1, nullptr, h_bf, M_, DFF_, D_);

    gemm_kernel<128, 128, 2><<<50 * (D_ / 128), 256, 0, stream>>>(
        h_bf, w2_bf, b2, x1, out, M_, D_, DFF_);
}

// Round 8
// 452.675 us; speedup vs baseline: 1.0135x; 1.0135x over previous
//
#include <hip/hip_runtime.h>
#include <hip/hip_bf16.h>
#include <math.h>

#define B_ 32
#define S_ 197
#define D_ 768
#define H_ 12
#define P_ 196
#define KN_ 32
#define HD_ 64
#define DFF_ 3072
#define M_ (B_ * S_)   // 6304

typedef __attribute__((ext_vector_type(8))) short short8;
typedef __attribute__((ext_vector_type(8))) __bf16 bf16x8;
typedef __attribute__((ext_vector_type(4))) float f32x4;
typedef __attribute__((ext_vector_type(4))) float float4v;

static __device__ __forceinline__ unsigned short f2bf(float f) {
    unsigned u = __builtin_bit_cast(unsigned, f);
    u += 0x7FFFu + ((u >> 16) & 1u);
    return (unsigned short)(u >> 16);
}
static __device__ __forceinline__ float bf2f(unsigned short s) {
    unsigned u = ((unsigned)s) << 16;
    return __builtin_bit_cast(float, u);
}

// async global -> LDS, 16 B per lane; LDS base wave-uniform (HW adds lane*16).
static __device__ __forceinline__ void gload_lds16(const void* g, void* l) {
    __builtin_amdgcn_global_load_lds(
        (const __attribute__((address_space(1))) unsigned int*)g,
        (__attribute__((address_space(3))) unsigned int*)l, 16, 0, 0);
}

// ---------- fused fp32->bf16 convert + transpose: in[K][N] -> out[N][K] ----------
__global__ void __launch_bounds__(256) cvt_t_kernel(const float* __restrict__ in,
        unsigned short* __restrict__ out, int K, int N) {
    __shared__ float tile[32][33];
    int nt = N >> 5;
    int bx = blockIdx.x % nt;
    int by = blockIdx.x / nt;
    int n0 = bx << 5, k0 = by << 5;
    int tx = threadIdx.x & 31, ty = threadIdx.x >> 5;
    #pragma unroll
    for (int i = 0; i < 32; i += 8)
        tile[ty + i][tx] = in[(size_t)(k0 + ty + i) * N + n0 + tx];
    __syncthreads();
    #pragma unroll
    for (int i = 0; i < 32; i += 8)
        out[(size_t)(n0 + ty + i) * K + k0 + tx] = f2bf(tile[tx][ty + i]);
}

// ---------------- LayerNorm (fp32 in, bf16 out) ----------------
__global__ void __launch_bounds__(256) ln_kernel(const float* __restrict__ x,
        const float* __restrict__ g, const float* __restrict__ bt,
        unsigned short* __restrict__ out) {
    int row = blockIdx.x;
    int tid = threadIdx.x;
    const float* xr = x + (size_t)row * D_;
    float v0 = xr[tid], v1 = xr[tid + 256], v2 = xr[tid + 512];
    float s = v0 + v1 + v2;
    float q = v0 * v0 + v1 * v1 + v2 * v2;
    #pragma unroll
    for (int o = 32; o >= 1; o >>= 1) {
        s += __shfl_xor(s, o);
        q += __shfl_xor(q, o);
    }
    __shared__ float red[8];
    int wave = tid >> 6, lane = tid & 63;
    if (lane == 0) { red[wave] = s; red[4 + wave] = q; }
    __syncthreads();
    float S0 = red[0] + red[1] + red[2] + red[3];
    float Q0 = red[4] + red[5] + red[6] + red[7];
    float mean = S0 * (1.0f / D_);
    float var = Q0 * (1.0f / D_) - mean * mean;
    float rstd = rsqrtf(var + 1e-5f);
    unsigned short* orow = out + (size_t)row * D_;
    orow[tid]       = f2bf((v0 - mean) * rstd * g[tid]       + bt[tid]);
    orow[tid + 256] = f2bf((v1 - mean) * rstd * g[tid + 256] + bt[tid + 256]);
    orow[tid + 512] = f2bf((v2 - mean) * rstd * g[tid + 512] + bt[tid + 512]);
}

// ======== 256x256 8-phase GEMM (HK-style schedule), 512 thr = 8 waves ========
// C = A[M,K] @ Bt[N,K]^T + bias.  EPI 0: bf16 store; 1: gelu->bf16.
// Even K-tiles in buf0, odd in buf1. Per phase: ds_read subtile + stage one
// half-tile + barrier + lgkmcnt(0) + 16 MFMA + barrier. vmcnt(2)/(4) at ph4/ph8.
#define DO_PHASE(X, MB, CA, RELOAD_B, CPN, ...)                               \
  {                                                                           \
    bf16x8 af_[4];                                                            \
    _Pragma("unroll")                                                         \
    for (int m_ = 0; m_ < 4; ++m_)                                            \
      af_[m_] = __builtin_bit_cast(bf16x8, *(const short8*)&As[X][ah][((MB) * 16 + m_ * 16 + lr) * 64 + (CA)]); \
    if (RELOAD_B) {                                                           \
      _Pragma("unroll")                                                       \
      for (int n_ = 0; n_ < 4; ++n_)                                          \
        bfr[n_] = __builtin_bit_cast(bf16x8, *(const short8*)&Bs[X][bh][(boff + n_ * 16 + lr) * 64 + (CA)]); \
    }                                                                         \
    __VA_ARGS__;                                                              \
    __builtin_amdgcn_s_barrier();                                             \
    asm volatile("s_waitcnt lgkmcnt(0)" ::: "memory");                        \
    __builtin_amdgcn_sched_barrier(0);                                        \
    __builtin_amdgcn_s_setprio(1);                                            \
    _Pragma("unroll")                                                         \
    for (int m_ = 0; m_ < 4; ++m_)                                            \
      _Pragma("unroll")                                                       \
      for (int n_ = 0; n_ < 4; ++n_)                                          \
        acc[(MB) + m_][n_] = __builtin_amdgcn_mfma_f32_16x16x32_bf16(         \
            af_[m_], bfr[n_], acc[(MB) + m_][n_], 0, 0, 0);                   \
    __builtin_amdgcn_s_setprio(0);                                            \
    if ((CPN) == 2) asm volatile("s_waitcnt vmcnt(2)" ::: "memory");          \
    if ((CPN) == 4) asm volatile("s_waitcnt vmcnt(4)" ::: "memory");          \
    __builtin_amdgcn_s_barrier();                                             \
  }

template<int EPI>
__global__ void __launch_bounds__(512, 1) gemm256_kernel(
        const unsigned short* __restrict__ A,
        const unsigned short* __restrict__ Bt,
        const float* __restrict__ bias,
        void* __restrict__ outp,
        int M, int N, int K) {
    __shared__ short As[2][2][8192];   // [buf][half][128 rows x 64 cols]
    __shared__ short Bs[2][2][8192];

    // bijective XCD-chunked swizzle (m204)
    int nwg = gridDim.x;
    int orig = blockIdx.x;
    int q8 = nwg >> 3, r8 = nwg & 7;
    int xcd = orig & 7, idx = orig >> 3;
    int wg = (xcd < r8 ? xcd * (q8 + 1) : r8 * (q8 + 1) + (xcd - r8) * q8) + idx;

    int ntn = N >> 8;
    int bm = (wg / ntn) << 8;
    int bn = (wg % ntn) << 8;
    int tid = threadIdx.x;
    int lane = tid & 63;
    int wave = tid >> 6;                 // 0..7
    int ah = wave >> 2;                  // A-half this wave reads
    int bh = (wave & 3) >> 1;            // B-half this wave reads
    int boff = (wave & 1) * 64;          // row offset within B-half
    int lr = lane & 15;
    int cA0 = ((lane >> 4) << 3) ^ ((lr & 7) << 3);        // kk=0 read col
    int cA1 = (32 + ((lane >> 4) << 3)) ^ ((lr & 7) << 3); // kk=1 read col
    int scol = (((lane & 7) ^ ((lane >> 3) & 7)) << 3);    // staged source col
    int srow = lane >> 3;                                  // row in 8-row chunk

    auto stageA = [&](int buf, int half, int kt) {
        #pragma unroll
        for (int cc = 0; cc < 2; ++cc) {
            int c = wave + cc * 8;
            int grow = bm + half * 128 + c * 8 + srow;
            if (grow >= M) grow = M - 1;  // row m of A only affects row m of C
            gload_lds16(A + (size_t)grow * K + kt + scol, &As[buf][half][c * 512]);
        }
    };
    auto stageB = [&](int buf, int half, int kt) {
        #pragma unroll
        for (int cc = 0; cc < 2; ++cc) {
            int c = wave + cc * 8;
            int grow = bn + half * 128 + c * 8 + srow;
            gload_lds16(Bt + (size_t)grow * K + kt + scol, &Bs[buf][half][c * 512]);
        }
    };

    f32x4 acc[8][4] = {};
    bf16x8 bfr[4];

    int nt = K >> 6;          // even (12 for K=768)
    int niter = nt >> 1;

    // prologue: tile0 fully + tile1's B halves; wait tile0 (last 4 may fly)
    stageA(0, 0, 0); stageA(0, 1, 0);
    stageB(0, 0, 0); stageB(0, 1, 0);
    stageB(1, 0, 64); stageB(1, 1, 64);
    asm volatile("s_waitcnt vmcnt(4)" ::: "memory");
    __builtin_amdgcn_s_barrier();

    for (int i = 0; i < niter; ++i) {
        int ktu = ((i << 1) + 1) << 6;                               // tile u
        int kt2 = ((i << 1) + 2 < nt ? (i << 1) + 2 : (i << 1)) << 6;
        int kt3 = ((i << 1) + 3 < nt ? (i << 1) + 3 : (i << 1) + 1) << 6;
        // tile t = 2i in buf0; tile u = 2i+1 in buf1
        DO_PHASE(0, 0, cA0, 1, -1, stageA(1, 0, ktu))                // ph1
        DO_PHASE(0, 4, cA0, 0, -1, stageA(1, 1, ktu))                // ph2
        DO_PHASE(0, 0, cA1, 1, -1, )                                 // ph3
        DO_PHASE(0, 4, cA1, 0,  2, stageB(0, 0, kt2))                // ph4 CP
        DO_PHASE(1, 0, cA0, 1, -1, stageB(0, 1, kt2); stageA(0, 0, kt2)) // ph5
        DO_PHASE(1, 4, cA0, 0, -1, stageA(0, 1, kt2))                // ph6
        DO_PHASE(1, 0, cA1, 1, -1, )                                 // ph7
        DO_PHASE(1, 4, cA1, 0,  4, stageB(1, 0, kt3); stageB(1, 1, kt3)) // ph8 CP
    }

    int r0 = (lane >> 4) << 2;
    int wmr = bm + ah * 128;
    int wnc = bn + (wave & 3) * 64;
    #pragma unroll
    for (int m = 0; m < 8; ++m) {
        #pragma unroll
        for (int n = 0; n < 4; ++n) {
            int col = wnc + n * 16 + lr;
            #pragma unroll
            for (int r = 0; r < 4; ++r) {
                int row = wmr + m * 16 + r0 + r;
                if (row < M) {
                    float v = acc[m][n][r] + bias[col];
                    if (EPI == 1)
                        v = 0.5f * v * (1.0f + erff(v * 0.70710678118f));
                    ((unsigned short*)outp)[(size_t)row * N + col] = f2bf(v);
                }
            }
        }
    }
}

// ------- 128-tile 2-phase GEMM (round-5 verified) for narrow-N layers -------
// EPI 2: +fp32 residual, store fp32.
template<int BM, int BN, int EPI>
__global__ void __launch_bounds__(256) gemm_kernel(
        const unsigned short* __restrict__ A,
        const unsigned short* __restrict__ Bt,
        const float* __restrict__ bias,
        const float* __restrict__ resid,
        void* __restrict__ outp,
        int M, int N, int K) {
    constexpr int BK = 64;
    constexpr int WM = BM / 2, WN = BN / 2;
    constexpr int MR = WM / 16, NR = WN / 16;
    constexpr int ACH = BM / 8;
    constexpr int BCH = BN / 8;
    constexpr int ASZ = BM * BK, BSZ = BN * BK;
    __shared__ short As[2 * ASZ];
    __shared__ short Bs[2 * BSZ];

    int nwg = gridDim.x;
    int orig = blockIdx.x;
    int q8 = nwg >> 3, r8 = nwg & 7;
    int xcd = orig & 7, idx = orig >> 3;
    int wg = (xcd < r8 ? xcd * (q8 + 1) : r8 * (q8 + 1) + (xcd - r8) * q8) + idx;

    int ntn = N / BN;
    int bm = (wg / ntn) * BM;
    int bn = (wg % ntn) * BN;
    int tid = threadIdx.x;
    int lane = tid & 63;
    int wave = tid >> 6;
    int wm = (wave >> 1) * WM, wn = (wave & 1) * WN;
    int lr = lane & 15;
    int lk0 = (lane >> 4) << 3;
    int crow = lane >> 3;
    int scol = (((lane & 7) ^ ((lane >> 3) & 7)) << 3);
    int rsw = (lr & 7) << 3;

    f32x4 acc[MR][NR] = {};

    auto stage = [&](int kt, int buf) {
        short* Ad = &As[buf * ASZ];
        short* Bd = &Bs[buf * BSZ];
        #pragma unroll
        for (int c = wave; c < ACH; c += 4) {
            int grow = bm + c * 8 + crow;
            if (grow >= M) grow = M - 1;
            gload_lds16(A + (size_t)grow * K + kt + scol, &Ad[c * 512]);
        }
        #pragma unroll
        for (int c = wave; c < BCH; c += 4) {
            int grow = bn + c * 8 + crow;
            gload_lds16(Bt + (size_t)grow * K + kt + scol, &Bd[c * 512]);
        }
    };

    int nt = K / BK;
    stage(0, 0);
    __syncthreads();

    for (int t = 0; t < nt; ++t) {
        int cur = t & 1;
        if (t + 1 < nt) stage((t + 1) * BK, cur ^ 1);
        const short* Ab = &As[cur * ASZ];
        const short* Bb = &Bs[cur * BSZ];
        __builtin_amdgcn_s_setprio(1);
        #pragma unroll
        for (int kk = 0; kk < 2; ++kk) {
            int lkb = lk0 + kk * 32;
            bf16x8 af[MR], bfv[NR];
            #pragma unroll
            for (int m = 0; m < MR; ++m)
                af[m] = __builtin_bit_cast(bf16x8,
                    *(const short8*)(&Ab[(wm + m * 16 + lr) * BK + (lkb ^ rsw)]));
            #pragma unroll
            for (int n = 0; n < NR; ++n)
                bfv[n] = __builtin_bit_cast(bf16x8,
                    *(const short8*)(&Bb[(wn + n * 16 + lr) * BK + (lkb ^ rsw)]));
            #pragma unroll
            for (int m = 0; m < MR; ++m)
                #pragma unroll
                for (int n = 0; n < NR; ++n)
                    acc[m][n] = __builtin_amdgcn_mfma_f32_16x16x32_bf16(
                        af[m], bfv[n], acc[m][n], 0, 0, 0);
        }
        __builtin_amdgcn_s_setprio(0);
        __syncthreads();
    }

    int r0 = (lane >> 4) << 2;
    #pragma unroll
    for (int m = 0; m < MR; ++m) {
        #pragma unroll
        for (int n = 0; n < NR; ++n) {
            int col = bn + wn + n * 16 + lr;
            #pragma unroll
            for (int r = 0; r < 4; ++r) {
                int row = bm + wm + m * 16 + r0 + r;
                if (row < M) {
                    float v = acc[m][n][r] + bias[col];
                    if (EPI == 1)
                        v = 0.5f * v * (1.0f + erff(v * 0.70710678118f));
                    if (EPI == 2) {
                        ((float*)outp)[(size_t)row * N + col] =
                            v + resid[(size_t)row * N + col];
                    } else {
                        ((unsigned short*)outp)[(size_t)row * N + col] = f2bf(v);
                    }
                }
            }
        }
    }
}

// ---------------- sparse patch attention: one wave per (b,h,p) ----------------
__global__ void __launch_bounds__(256) attn_patch_kernel(
        const unsigned short* __restrict__ qkv,
        const int* __restrict__ routes,
        unsigned short* __restrict__ out) {
    int wid = (blockIdx.x * 256 + threadIdx.x) >> 6;
    int lane = threadIdx.x & 63;
    int b = wid / (H_ * P_);
    int rem = wid - b * (H_ * P_);
    int h = rem / P_;
    int p = rem - h * P_;
    int ks = lane & 31, half = lane >> 5;
    int skey = routes[p * KN_ + ks] + 1;
    const unsigned short* Qrow = qkv + (size_t)(b * S_ + p + 1) * (3 * D_) + h * HD_;
    const unsigned short* Krow = qkv + (size_t)(b * S_ + skey) * (3 * D_) + D_ + h * HD_;
    float dot = 0.f;
    #pragma unroll
    for (int q = 0; q < 4; ++q) {
        short8 qv = *(const short8*)(Qrow + half * 32 + q * 8);
        short8 kv = *(const short8*)(Krow + half * 32 + q * 8);
        #pragma unroll
        for (int j = 0; j < 8; ++j)
            dot += bf2f((unsigned short)qv[j]) * bf2f((unsigned short)kv[j]);
    }
    dot += __shfl_xor(dot, 32);
    float sc = dot * 0.125f;
    float mx = sc;
    #pragma unroll
    for (int o = 16; o >= 1; o >>= 1) mx = fmaxf(mx, __shfl_xor(mx, o));
    float e = __expf(sc - mx);
    float ssum = e;
    #pragma unroll
    for (int o = 16; o >= 1; o >>= 1) ssum += __shfl_xor(ssum, o);
    float w = e / ssum;
    const unsigned short* Vb = qkv + (size_t)b * S_ * (3 * D_) + 2 * D_ + h * HD_;
    float o_acc = 0.f;
    #pragma unroll 4
    for (int k = 0; k < 32; ++k) {
        float wk = __shfl(w, k);
        int sk = __shfl(skey, k);
        o_acc += wk * bf2f(Vb[(size_t)sk * (3 * D_) + lane]);
    }
    out[(size_t)(b * S_ + p + 1) * D_ + h * HD_ + lane] = f2bf(o_acc);
}

// ---------------- dense CLS attention: one wave per (b,h) ----------------
__global__ void __launch_bounds__(256) attn_cls_kernel(
        const unsigned short* __restrict__ qkv,
        unsigned short* __restrict__ out) {
    int wid = (blockIdx.x * 256 + threadIdx.x) >> 6;
    int lane = threadIdx.x & 63;
    int b = wid / H_, h = wid - b * H_;
    int ks = lane & 31, half = lane >> 5;
    const unsigned short* base = qkv + (size_t)b * S_ * (3 * D_);
    const unsigned short* Qrow = base + h * HD_;
    short8 qv[4];
    #pragma unroll
    for (int q = 0; q < 4; ++q)
        qv[q] = *(const short8*)(Qrow + half * 32 + q * 8);
    float sc[7];
    #pragma unroll
    for (int c = 0; c < 7; ++c) {
        int key = c * 32 + ks;
        float dot = 0.f;
        if (key < S_) {
            const unsigned short* Krow =
                base + (size_t)key * (3 * D_) + D_ + h * HD_ + half * 32;
            #pragma unroll
            for (int q = 0; q < 4; ++q) {
                short8 kv = *(const short8*)(Krow + q * 8);
                #pragma unroll
                for (int j = 0; j < 8; ++j)
                    dot += bf2f((unsigned short)qv[q][j]) * bf2f((unsigned short)kv[j]);
            }
        }
        dot += __shfl_xor(dot, 32);
        sc[c] = (key < S_) ? dot * 0.125f : -1e30f;
    }
    float mx = -1e30f;
    #pragma unroll
    for (int c = 0; c < 7; ++c) mx = fmaxf(mx, sc[c]);
    #pragma unroll
    for (int o = 16; o >= 1; o >>= 1) mx = fmaxf(mx, __shfl_xor(mx, o));
    float e[7];
    float ssum = 0.f;
    #pragma unroll
    for (int c = 0; c < 7; ++c) { e[c] = __expf(sc[c] - mx); ssum += e[c]; }
    #pragma unroll
    for (int o = 16; o >= 1; o >>= 1) ssum += __shfl_xor(ssum, o);
    float inv = 1.f / ssum;
    const unsigned short* Vb = base + 2 * D_ + h * HD_;
    float o_acc = 0.f;
    for (int c = 0; c < 7; ++c) {
        for (int k = 0; k < 32; ++k) {
            int key = c * 32 + k;
            if (key < S_) {
                float wk = __shfl(e[c], k) * inv;
                o_acc += wk * bf2f(Vb[(size_t)key * (3 * D_) + lane]);
            }
        }
    }
    out[(size_t)(b * S_) * D_ + h * HD_ + lane] = f2bf(o_acc);
}

extern "C" void kernel_launch(void* const* d_in, const int* in_sizes, int n_in,
                              void* d_out, int out_size, void* d_ws, size_t ws_size,
                              hipStream_t stream) {
    const float* x      = (const float*)d_in[0];
    const int*   routes = (const int*)d_in[1];
    const float* qkv_w  = (const float*)d_in[2];
    const float* qkv_b  = (const float*)d_in[3];
    const float* proj_w = (const float*)d_in[4];
    const float* proj_b = (const float*)d_in[5];
    const float* n1_g   = (const float*)d_in[6];
    const float* n1_b   = (const float*)d_in[7];
    const float* n2_g   = (const float*)d_in[8];
    const float* n2_b   = (const float*)d_in[9];
    const float* w1     = (const float*)d_in[10];
    const float* b1     = (const float*)d_in[11];
    const float* w2     = (const float*)d_in[12];
    const float* b2     = (const float*)d_in[13];
    float* out = (float*)d_out;

    char* ws = (char*)d_ws;
    size_t off = 0;
    auto alloc = [&](size_t bytes) -> void* {
        void* p = ws + off;
        off += (bytes + 255) & ~(size_t)255;
        return p;
    };
    unsigned short* wq_bf  = (unsigned short*)alloc((size_t)D_ * 3 * D_ * 2);
    unsigned short* wp_bf  = (unsigned short*)alloc((size_t)D_ * D_ * 2);
    unsigned short* w1_bf  = (unsigned short*)alloc((size_t)D_ * DFF_ * 2);
    unsigned short* w2_bf  = (unsigned short*)alloc((size_t)DFF_ * D_ * 2);
    unsigned short* xn_bf  = (unsigned short*)alloc((size_t)M_ * D_ * 2);
    float*          x1     = (float*)alloc((size_t)M_ * D_ * 4);
    unsigned short* qkv_bf = (unsigned short*)alloc((size_t)M_ * 3 * D_ * 2);
    unsigned short* attn_bf= (unsigned short*)alloc((size_t)M_ * D_ * 2);
    unsigned short* h_bf   = qkv_bf;   // reuse (dead after attention)

    auto cvt_t = [&](const float* src, unsigned short* dst, int K, int N) {
        cvt_t_kernel<<<(N >> 5) * (K >> 5), 256, 0, stream>>>(src, dst, K, N);
    };
    cvt_t(qkv_w, wq_bf, D_, 3 * D_);
    cvt_t(proj_w, wp_bf, D_, D_);
    cvt_t(w1, w1_bf, D_, DFF_);
    cvt_t(w2, w2_bf, DFF_, D_);

    ln_kernel<<<M_, 256, 0, stream>>>(x, n1_g, n1_b, xn_bf);

    // qkv: 256^2 8-phase, grid 25 x 9 = 225
    gemm256_kernel<0><<<25 * (3 * D_ / 256), 512, 0, stream>>>(
        xn_bf, wq_bf, qkv_b, qkv_bf, M_, 3 * D_, D_);

    attn_patch_kernel<<<(B_ * H_ * P_) / 4, 256, 0, stream>>>(qkv_bf, routes, attn_bf);
    attn_cls_kernel<<<(B_ * H_) / 4, 256, 0, stream>>>(qkv_bf, attn_bf);

    gemm_kernel<128, 64, 2><<<50 * (D_ / 64), 256, 0, stream>>>(
        attn_bf, wp_bf, proj_b, x, x1, M_, D_, D_);

    ln_kernel<<<M_, 256, 0, stream>>>(x1, n2_g, n2_b, xn_bf);

    // mlp1: 256^2 8-phase, grid 25 x 12 = 300
    gemm256_kernel<1><<<25 * (DFF_ / 256), 512, 0, stream>>>(
        xn_bf, w1_bf, b1, h_bf, M_, DFF_, D_);

    gemm_kernel<128, 64, 2><<<50 * (D_ / 64), 256, 0, stream>>>(
        h_bf, w2_bf, b2, x1, out, M_, D_, DFF_);
}

// Round 9
// 404.537 us; speedup vs baseline: 1.1341x; 1.1190x over previous
//
#include <hip/hip_runtime.h>
#include <hip/hip_bf16.h>
#include <math.h>

#define B_ 32
#define S_ 197
#define D_ 768
#define H_ 12
#define P_ 196
#define KN_ 32
#define HD_ 64
#define DFF_ 3072
#define M_ (B_ * S_)   // 6304

typedef __attribute__((ext_vector_type(8))) short short8;
typedef __attribute__((ext_vector_type(8))) __bf16 bf16x8;
typedef __attribute__((ext_vector_type(4))) float f32x4;
typedef __attribute__((ext_vector_type(4))) float float4v;

static __device__ __forceinline__ unsigned short f2bf(float f) {
    unsigned u = __builtin_bit_cast(unsigned, f);
    u += 0x7FFFu + ((u >> 16) & 1u);
    return (unsigned short)(u >> 16);
}
static __device__ __forceinline__ float bf2f(unsigned short s) {
    unsigned u = ((unsigned)s) << 16;
    return __builtin_bit_cast(float, u);
}

// async global -> LDS, 16 B per lane; LDS base wave-uniform (HW adds lane*16).
static __device__ __forceinline__ void gload_lds16(const void* g, void* l) {
    __builtin_amdgcn_global_load_lds(
        (const __attribute__((address_space(1))) unsigned int*)g,
        (__attribute__((address_space(3))) unsigned int*)l, 16, 0, 0);
}

// ---------- fused fp32->bf16 convert + transpose: in[K][N] -> out[N][K] ----------
__global__ void __launch_bounds__(256) cvt_t_kernel(const float* __restrict__ in,
        unsigned short* __restrict__ out, int K, int N) {
    __shared__ float tile[32][33];
    int nt = N >> 5;
    int bx = blockIdx.x % nt;
    int by = blockIdx.x / nt;
    int n0 = bx << 5, k0 = by << 5;
    int tx = threadIdx.x & 31, ty = threadIdx.x >> 5;
    #pragma unroll
    for (int i = 0; i < 32; i += 8)
        tile[ty + i][tx] = in[(size_t)(k0 + ty + i) * N + n0 + tx];
    __syncthreads();
    #pragma unroll
    for (int i = 0; i < 32; i += 8)
        out[(size_t)(n0 + ty + i) * K + k0 + tx] = f2bf(tile[tx][ty + i]);
}

// ---------------- LayerNorm (fp32 in, bf16 out) ----------------
__global__ void __launch_bounds__(256) ln_kernel(const float* __restrict__ x,
        const float* __restrict__ g, const float* __restrict__ bt,
        unsigned short* __restrict__ out) {
    int row = blockIdx.x;
    int tid = threadIdx.x;
    const float* xr = x + (size_t)row * D_;
    float v0 = xr[tid], v1 = xr[tid + 256], v2 = xr[tid + 512];
    float s = v0 + v1 + v2;
    float q = v0 * v0 + v1 * v1 + v2 * v2;
    #pragma unroll
    for (int o = 32; o >= 1; o >>= 1) {
        s += __shfl_xor(s, o);
        q += __shfl_xor(q, o);
    }
    __shared__ float red[8];
    int wave = tid >> 6, lane = tid & 63;
    if (lane == 0) { red[wave] = s; red[4 + wave] = q; }
    __syncthreads();
    float S0 = red[0] + red[1] + red[2] + red[3];
    float Q0 = red[4] + red[5] + red[6] + red[7];
    float mean = S0 * (1.0f / D_);
    float var = Q0 * (1.0f / D_) - mean * mean;
    float rstd = rsqrtf(var + 1e-5f);
    unsigned short* orow = out + (size_t)row * D_;
    orow[tid]       = f2bf((v0 - mean) * rstd * g[tid]       + bt[tid]);
    orow[tid + 256] = f2bf((v1 - mean) * rstd * g[tid + 256] + bt[tid + 256]);
    orow[tid + 512] = f2bf((v2 - mean) * rstd * g[tid + 512] + bt[tid + 512]);
}

// ------- bf16 MFMA GEMM (m97 structure): C = A[M,K] @ Bt[N,K]^T + bias -------
// Single-buffered BK=64 tile, global_load_lds staging, both-sides XOR swizzle,
// 2 barriers/K-step; latency hidden by 5-6 resident blocks/CU (TLP).
// EPI 0: store bf16.  EPI 1: gelu(exact)->bf16.  EPI 2: +fp32 resid, fp32.
template<int BM, int BN, int EPI>
__global__ void __launch_bounds__(256) gemm_kernel(
        const unsigned short* __restrict__ A,
        const unsigned short* __restrict__ Bt,
        const float* __restrict__ bias,
        const float* __restrict__ resid,
        void* __restrict__ outp,
        int M, int N, int K) {
    constexpr int BK = 64;
    constexpr int WM = BM / 2, WN = BN / 2;
    constexpr int MR = WM / 16, NR = WN / 16;
    constexpr int ACH = BM / 8;   // 1KB chunks (8 rows x 128B)
    constexpr int BCH = BN / 8;
    __shared__ short As[BM * BK];
    __shared__ short Bs[BN * BK];

    // bijective XCD-chunked swizzle (m204)
    int nwg = gridDim.x;
    int orig = blockIdx.x;
    int q8 = nwg >> 3, r8 = nwg & 7;
    int xcd = orig & 7, idx = orig >> 3;
    int wg = (xcd < r8 ? xcd * (q8 + 1) : r8 * (q8 + 1) + (xcd - r8) * q8) + idx;

    int ntn = N / BN;
    int bm = (wg / ntn) * BM;
    int bn = (wg % ntn) * BN;
    int tid = threadIdx.x;
    int lane = tid & 63;
    int wave = tid >> 6;
    int wm = (wave >> 1) * WM, wn = (wave & 1) * WN;
    int lr = lane & 15;
    int lk0 = (lane >> 4) << 3;               // 0,8,16,24 (shorts)
    int crow = lane >> 3;                     // row within 8-row chunk
    // pre-swizzled source col (shorts): involution of the read-side XOR
    int scol = (((lane & 7) ^ ((lane >> 3) & 7)) << 3);
    int rsw = (lr & 7) << 3;                  // read-side XOR (shorts)

    f32x4 acc[MR][NR] = {};

    for (int kt = 0; kt < K; kt += BK) {
        #pragma unroll
        for (int c = wave; c < ACH; c += 4) {
            int grow = bm + c * 8 + crow;
            if (grow >= M) grow = M - 1;   // row m of A only affects row m of C
            gload_lds16(A + (size_t)grow * K + kt + scol, &As[c * 512]);
        }
        #pragma unroll
        for (int c = wave; c < BCH; c += 4) {
            int grow = bn + c * 8 + crow;
            gload_lds16(Bt + (size_t)grow * K + kt + scol, &Bs[c * 512]);
        }
        __syncthreads();   // drains vmcnt(0) before s_barrier (compiler)
        #pragma unroll
        for (int kk = 0; kk < 2; ++kk) {
            int lkb = lk0 + kk * 32;
            bf16x8 af[MR], bfv[NR];
            #pragma unroll
            for (int m = 0; m < MR; ++m)
                af[m] = __builtin_bit_cast(bf16x8,
                    *(const short8*)(&As[(wm + m * 16 + lr) * BK + (lkb ^ rsw)]));
            #pragma unroll
            for (int n = 0; n < NR; ++n)
                bfv[n] = __builtin_bit_cast(bf16x8,
                    *(const short8*)(&Bs[(wn + n * 16 + lr) * BK + (lkb ^ rsw)]));
            #pragma unroll
            for (int m = 0; m < MR; ++m)
                #pragma unroll
                for (int n = 0; n < NR; ++n)
                    acc[m][n] = __builtin_amdgcn_mfma_f32_16x16x32_bf16(
                        af[m], bfv[n], acc[m][n], 0, 0, 0);
        }
        __syncthreads();   // reads done before next stage overwrites
    }

    int r0 = (lane >> 4) << 2;
    #pragma unroll
    for (int m = 0; m < MR; ++m) {
        #pragma unroll
        for (int n = 0; n < NR; ++n) {
            int col = bn + wn + n * 16 + lr;
            #pragma unroll
            for (int r = 0; r < 4; ++r) {
                int row = bm + wm + m * 16 + r0 + r;
                if (row < M) {
                    float v = acc[m][n][r] + bias[col];
                    if (EPI == 1)
                        v = 0.5f * v * (1.0f + erff(v * 0.70710678118f));
                    if (EPI == 2) {
                        ((float*)outp)[(size_t)row * N + col] =
                            v + resid[(size_t)row * N + col];
                    } else {
                        ((unsigned short*)outp)[(size_t)row * N + col] = f2bf(v);
                    }
                }
            }
        }
    }
}

// ---------------- sparse patch attention: one wave per (b,h,p) ----------------
__global__ void __launch_bounds__(256) attn_patch_kernel(
        const unsigned short* __restrict__ qkv,
        const int* __restrict__ routes,
        unsigned short* __restrict__ out) {
    int wid = (blockIdx.x * 256 + threadIdx.x) >> 6;
    int lane = threadIdx.x & 63;
    int b = wid / (H_ * P_);
    int rem = wid - b * (H_ * P_);
    int h = rem / P_;
    int p = rem - h * P_;
    int ks = lane & 31, half = lane >> 5;
    int skey = routes[p * KN_ + ks] + 1;
    const unsigned short* Qrow = qkv + (size_t)(b * S_ + p + 1) * (3 * D_) + h * HD_;
    const unsigned short* Krow = qkv + (size_t)(b * S_ + skey) * (3 * D_) + D_ + h * HD_;
    float dot = 0.f;
    #pragma unroll
    for (int q = 0; q < 4; ++q) {
        short8 qv = *(const short8*)(Qrow + half * 32 + q * 8);
        short8 kv = *(const short8*)(Krow + half * 32 + q * 8);
        #pragma unroll
        for (int j = 0; j < 8; ++j)
            dot += bf2f((unsigned short)qv[j]) * bf2f((unsigned short)kv[j]);
    }
    dot += __shfl_xor(dot, 32);
    float sc = dot * 0.125f;
    float mx = sc;
    #pragma unroll
    for (int o = 16; o >= 1; o >>= 1) mx = fmaxf(mx, __shfl_xor(mx, o));
    float e = __expf(sc - mx);
    float ssum = e;
    #pragma unroll
    for (int o = 16; o >= 1; o >>= 1) ssum += __shfl_xor(ssum, o);
    float w = e / ssum;
    const unsigned short* Vb = qkv + (size_t)b * S_ * (3 * D_) + 2 * D_ + h * HD_;
    float o_acc = 0.f;
    #pragma unroll 4
    for (int k = 0; k < 32; ++k) {
        float wk = __shfl(w, k);
        int sk = __shfl(skey, k);
        o_acc += wk * bf2f(Vb[(size_t)sk * (3 * D_) + lane]);
    }
    out[(size_t)(b * S_ + p + 1) * D_ + h * HD_ + lane] = f2bf(o_acc);
}

// ---------------- dense CLS attention: one wave per (b,h) ----------------
__global__ void __launch_bounds__(256) attn_cls_kernel(
        const unsigned short* __restrict__ qkv,
        unsigned short* __restrict__ out) {
    int wid = (blockIdx.x * 256 + threadIdx.x) >> 6;
    int lane = threadIdx.x & 63;
    int b = wid / H_, h = wid - b * H_;
    int ks = lane & 31, half = lane >> 5;
    const unsigned short* base = qkv + (size_t)b * S_ * (3 * D_);
    const unsigned short* Qrow = base + h * HD_;
    short8 qv[4];
    #pragma unroll
    for (int q = 0; q < 4; ++q)
        qv[q] = *(const short8*)(Qrow + half * 32 + q * 8);
    float sc[7];
    #pragma unroll
    for (int c = 0; c < 7; ++c) {
        int key = c * 32 + ks;
        float dot = 0.f;
        if (key < S_) {
            const unsigned short* Krow =
                base + (size_t)key * (3 * D_) + D_ + h * HD_ + half * 32;
            #pragma unroll
            for (int q = 0; q < 4; ++q) {
                short8 kv = *(const short8*)(Krow + q * 8);
                #pragma unroll
                for (int j = 0; j < 8; ++j)
                    dot += bf2f((unsigned short)qv[q][j]) * bf2f((unsigned short)kv[j]);
            }
        }
        dot += __shfl_xor(dot, 32);
        sc[c] = (key < S_) ? dot * 0.125f : -1e30f;
    }
    float mx = -1e30f;
    #pragma unroll
    for (int c = 0; c < 7; ++c) mx = fmaxf(mx, sc[c]);
    #pragma unroll
    for (int o = 16; o >= 1; o >>= 1) mx = fmaxf(mx, __shfl_xor(mx, o));
    float e[7];
    float ssum = 0.f;
    #pragma unroll
    for (int c = 0; c < 7; ++c) { e[c] = __expf(sc[c] - mx); ssum += e[c]; }
    #pragma unroll
    for (int o = 16; o >= 1; o >>= 1) ssum += __shfl_xor(ssum, o);
    float inv = 1.f / ssum;
    const unsigned short* Vb = base + 2 * D_ + h * HD_;
    float o_acc = 0.f;
    for (int c = 0; c < 7; ++c) {
        for (int k = 0; k < 32; ++k) {
            int key = c * 32 + k;
            if (key < S_) {
                float wk = __shfl(e[c], k) * inv;
                o_acc += wk * bf2f(Vb[(size_t)key * (3 * D_) + lane]);
            }
        }
    }
    out[(size_t)(b * S_) * D_ + h * HD_ + lane] = f2bf(o_acc);
}

extern "C" void kernel_launch(void* const* d_in, const int* in_sizes, int n_in,
                              void* d_out, int out_size, void* d_ws, size_t ws_size,
                              hipStream_t stream) {
    const float* x      = (const float*)d_in[0];
    const int*   routes = (const int*)d_in[1];
    const float* qkv_w  = (const float*)d_in[2];
    const float* qkv_b  = (const float*)d_in[3];
    const float* proj_w = (const float*)d_in[4];
    const float* proj_b = (const float*)d_in[5];
    const float* n1_g   = (const float*)d_in[6];
    const float* n1_b   = (const float*)d_in[7];
    const float* n2_g   = (const float*)d_in[8];
    const float* n2_b   = (const float*)d_in[9];
    const float* w1     = (const float*)d_in[10];
    const float* b1     = (const float*)d_in[11];
    const float* w2     = (const float*)d_in[12];
    const float* b2     = (const float*)d_in[13];
    float* out = (float*)d_out;

    char* ws = (char*)d_ws;
    size_t off = 0;
    auto alloc = [&](size_t bytes) -> void* {
        void* p = ws + off;
        off += (bytes + 255) & ~(size_t)255;
        return p;
    };
    unsigned short* wq_bf  = (unsigned short*)alloc((size_t)D_ * 3 * D_ * 2);
    unsigned short* wp_bf  = (unsigned short*)alloc((size_t)D_ * D_ * 2);
    unsigned short* w1_bf  = (unsigned short*)alloc((size_t)D_ * DFF_ * 2);
    unsigned short* w2_bf  = (unsigned short*)alloc((size_t)DFF_ * D_ * 2);
    unsigned short* xn_bf  = (unsigned short*)alloc((size_t)M_ * D_ * 2);
    float*          x1     = (float*)alloc((size_t)M_ * D_ * 4);
    unsigned short* qkv_bf = (unsigned short*)alloc((size_t)M_ * 3 * D_ * 2);
    unsigned short* attn_bf= (unsigned short*)alloc((size_t)M_ * D_ * 2);
    unsigned short* h_bf   = qkv_bf;   // reuse (dead after attention)

    auto cvt_t = [&](const float* src, unsigned short* dst, int K, int N) {
        cvt_t_kernel<<<(N >> 5) * (K >> 5), 256, 0, stream>>>(src, dst, K, N);
    };
    cvt_t(qkv_w, wq_bf, D_, 3 * D_);
    cvt_t(proj_w, wp_bf, D_, D_);
    cvt_t(w1, w1_bf, D_, DFF_);
    cvt_t(w2, w2_bf, DFF_, D_);

    ln_kernel<<<M_, 256, 0, stream>>>(x, n1_g, n1_b, xn_bf);

    gemm_kernel<128, 128, 0><<<50 * (3 * D_ / 128), 256, 0, stream>>>(
        xn_bf, wq_bf, qkv_b, nullptr, qkv_bf, M_, 3 * D_, D_);

    attn_patch_kernel<<<(B_ * H_ * P_) / 4, 256, 0, stream>>>(qkv_bf, routes, attn_bf);
    attn_cls_kernel<<<(B_ * H_) / 4, 256, 0, stream>>>(qkv_bf, attn_bf);

    gemm_kernel<128, 64, 2><<<50 * (D_ / 64), 256, 0, stream>>>(
        attn_bf, wp_bf, proj_b, x, x1, M_, D_, D_);

    ln_kernel<<<M_, 256, 0, stream>>>(x1, n2_g, n2_b, xn_bf);

    gemm_kernel<128, 128, 1><<<50 * (DFF_ / 128), 256, 0, stream>>>(
        xn_bf, w1_bf, b1, nullptr, h_bf, M_, DFF_, D_);

    gemm_kernel<128, 64, 2><<<50 * (D_ / 64), 256, 0, stream>>>(
        h_bf, w2_bf, b2, x1, out, M_, D_, DFF_);
}